// Round 6
// baseline (306.900 us; speedup 1.0000x reference)
//
#include <hip/hip_runtime.h>

#define Bsz 1024
#define Tt  256
#define Vv  32004
#define Dd  50
#define Hh  64
#define MB  128  // vocab rows per build_tables block

typedef __bf16 b16x8 __attribute__((ext_vector_type(8)));
typedef float  f32x4 __attribute__((ext_vector_type(4)));

// barrier WITHOUT vmcnt(0) drain: LDS ordering only, in-flight global loads
// (the xw register prefetch) survive across it.
__device__ __forceinline__ void barrier_novm() {
    asm volatile("s_waitcnt lgkmcnt(0)\n\ts_barrier" ::: "memory");
}
// Fast activations via raw gfx950 opcodes: v_exp_f32 = 2^x, v_rcp_f32 = 1/x.
// (IEEE fp32 div w/o -ffast-math = ~10 dependent VALU each; this was ~300 cyc
// of the step. Verified win in round 5: lstm 236 -> 190 us.)
__device__ __forceinline__ float fexp2(float x) {
    float r;
    asm("v_exp_f32 %0, %1" : "=v"(r) : "v"(x));
    return r;
}
__device__ __forceinline__ float frcp(float x) {
    float r;
    asm("v_rcp_f32 %0, %1" : "=v"(r) : "v"(x));
    return r;
}
__device__ __forceinline__ float fsig(float x) {
    return frcp(1.0f + fexp2(x * -1.442695041f));                // 1/(1+e^-x)
}
__device__ __forceinline__ float ftanh(float x) {
    return 2.0f * frcp(1.0f + fexp2(x * -2.885390082f)) - 1.0f;  // 2/(1+e^-2x)-1
}

// fp32 -> bf16 hi/lo split (3-term product keeps ~fp32 accuracy)
__device__ __forceinline__ void cvt_hilo(const float* x, b16x8& hi, b16x8& lo) {
#pragma unroll
    for (int e = 0; e < 8; ++e) {
        const __bf16 h = (__bf16)x[e];
        hi[e] = h;
        lo[e] = (__bf16)(x[e] - (float)h);
    }
}

// ---------------------------------------------------------------------------
// Prologue v5: tab[v][unit*4+gate] = emb[v,:] . Wih[g,:] + bias, via MFMA.
// Round-5 post-mortem: the ~93us was NOT stores (coalescing them moved -5us);
// it is the ~100 SCATTERED per-lane fragment loads per thread (200B row
// stride -> each wave-load touches dozens of cache lines, TA-serialized).
// Fix: flat fully-coalesced float4 copies of Wih (51.2KB) and a 128-row emb
// tile (25.6KB) into LDS (~20 VMEM/thread), fragments built from LDS.
// MB 64->128 halves per-output B-frag cost. LDS 76.8KB -> 2 blocks/CU.
// ---------------------------------------------------------------------------
__launch_bounds__(256)
__global__ void build_tables(const float* __restrict__ emb,
                             const float* __restrict__ Wih1,
                             const float* __restrict__ bih1,
                             const float* __restrict__ bhh1,
                             const float* __restrict__ Wih2,
                             const float* __restrict__ bih2,
                             const float* __restrict__ bhh2,
                             float* __restrict__ tab1,
                             float* __restrict__ tab2) {
    const int tid  = threadIdx.x;
    const int w    = tid >> 6;        // wave: unit tile 16w..16w+15
    const int lane = tid & 63;
    const int q    = lane >> 4;
    const int mn   = lane & 15;
    const int v0   = blockIdx.x * MB;

    const float* Wih = blockIdx.y ? Wih2 : Wih1;
    const float* bih = blockIdx.y ? bih2 : bih1;
    const float* bhh = blockIdx.y ? bhh2 : bhh1;
    float*       tab = blockIdx.y ? tab2 : tab1;

    __shared__ __align__(16) float wlds[256 * Dd];   // 51.2 KB, flat row-major
    __shared__ __align__(16) float elds[MB * Dd];    // 25.6 KB, flat row-major

    // flat coalesced staging: Wih = 12800 dwords = 3200 float4
    for (int d4 = tid; d4 < 256 * Dd / 4; d4 += 256)
        *(float4*)&wlds[4 * d4] = *(const float4*)(Wih + 4 * d4);
    // emb tile: 6400 dwords = 1600 float4, clamped at the vocab end
    {
        const int ebase = v0 * Dd;
        const int elim  = Vv * Dd - ebase;   // valid dwords from ebase
        const int mx    = Vv * Dd - 1;
        for (int d4 = tid; d4 < MB * Dd / 4; d4 += 256) {
            const int d = 4 * d4;
            float4 v;
            if (d + 4 <= elim) {
                v = *(const float4*)(emb + ebase + d);
            } else {
                v.x = emb[min(ebase + d,     mx)];
                v.y = emb[min(ebase + d + 1, mx)];
                v.z = emb[min(ebase + d + 2, mx)];
                v.w = emb[min(ebase + d + 3, mx)];
            }
            *(float4*)&elds[d] = v;
        }
    }
    __syncthreads();

    // B fragments (Wih^T) from LDS, gate-type k: B[kd=8q+j][n=mn]
    b16x8 bh[4][2], bl[4][2];
    f32x4 bias4;
#pragma unroll
    for (int k = 0; k < 4; ++k) {
        const int g = 64 * k + 16 * w + mn;
        const int base = g * Dd;
        float x[8];
#pragma unroll
        for (int j = 0; j < 8; ++j) x[j] = wlds[base + 8 * q + j];   // cols<32
        cvt_hilo(x, bh[k][0], bl[k][0]);
#pragma unroll
        for (int j = 0; j < 8; ++j) {
            const int col = 32 + 8 * q + j;
            x[j] = (col < Dd) ? wlds[base + col] : 0.0f;
        }
        cvt_hilo(x, bh[k][1], bl[k][1]);
        bias4[k] = bih[g] + bhh[g];
    }

#pragma unroll 1
    for (int m = 0; m < MB / 16; ++m) {
        // A fragment from LDS: A[mr=mn][kd] = emb[v0+16m+mn][kd]
        const int base = (16 * m + mn) * Dd;
        b16x8 ah[2], al[2];
        float x[8];
#pragma unroll
        for (int j = 0; j < 8; ++j) x[j] = elds[base + 8 * q + j];
        cvt_hilo(x, ah[0], al[0]);
#pragma unroll
        for (int j = 0; j < 8; ++j) {
            const int col = 32 + 8 * q + j;
            x[j] = (col < Dd) ? elds[base + col] : 0.0f;
        }
        cvt_hilo(x, ah[1], al[1]);

        f32x4 acc[4];
#pragma unroll
        for (int k = 0; k < 4; ++k) {
            f32x4 a = {0.0f, 0.0f, 0.0f, 0.0f};
#pragma unroll
            for (int kh = 0; kh < 2; ++kh) {
                a = __builtin_amdgcn_mfma_f32_16x16x32_bf16(ah[kh], bh[k][kh], a, 0, 0, 0);
                a = __builtin_amdgcn_mfma_f32_16x16x32_bf16(ah[kh], bl[k][kh], a, 0, 0, 0);
                a = __builtin_amdgcn_mfma_f32_16x16x32_bf16(al[kh], bh[k][kh], a, 0, 0, 0);
            }
            acc[k] = a;
        }
        // store: one contiguous float4 {i,f,g,o}+bias per (lane, r)
#pragma unroll
        for (int r = 0; r < 4; ++r) {
            const int vr = v0 + 16 * m + 4 * q + r;
            if (vr < Vv) {
                f32x4 o;
                o[0] = acc[0][r] + bias4[0];
                o[1] = acc[1][r] + bias4[1];
                o[2] = acc[2][r] + bias4[2];
                o[3] = acc[3][r] + bias4[3];
                *(f32x4*)(tab + (size_t)vr * 256 + (16 * w + mn) * 4) = o;
            }
        }
    }
}

// ---------------------------------------------------------------------------
// v6 recurrence: v5 structure (256 blocks x 4 rows, 4 waves, in-register
// gates, 1 novm-barrier/step, unit-major tab, distance-4 prefetch) with two
// chain trims: (a) all 8 MFMAs independent (zero-C) -- removes one dependent
// MFMA latency (K-halves summed after pick); (b) S-refill issues at step
// START into a temp (was blocked behind the MFMA-dependent gate adds).
// ---------------------------------------------------------------------------
__launch_bounds__(256, 1)
__global__ void lstm_main(const int*   __restrict__ s1,
                          const int*   __restrict__ s2,
                          const int*   __restrict__ len1,
                          const int*   __restrict__ len2,
                          const float* __restrict__ tab1,
                          const float* __restrict__ tab2,
                          const float* __restrict__ Whh1,
                          const float* __restrict__ Whh2,
                          const float* __restrict__ Wl1,
                          const float* __restrict__ bl1,
                          const float* __restrict__ Wl2,
                          const float* __restrict__ bl2,
                          float* __restrict__ out) {
    const int tid  = threadIdx.x;
    const int w    = tid >> 6;        // wave: unit tile [16w,16w+16)
    const int lane = tid & 63;
    const int q    = lane >> 4;       // MFMA quad
    const int mn   = lane & 15;       // B/C column
    const int row  = mn & 3;          // batch row within block
    const bool sb0 = (mn >> 2) & 1;   // rsel bit0
    const bool sb1 = (mn >> 3) & 1;   // rsel bit1
    const int u_own = 16 * w + 4 * q + (mn >> 2);  // this lane's hidden unit
    const int b0   = blockIdx.x * 4;

    __shared__ __align__(16) __bf16 hsh[2][4][96];  // row stride 192B: 2-way banks
    __shared__ int   toklds[Tt][4];                 // transposed: uniform-t read
    __shared__ float h2s[4][64];
    __shared__ float ys[4][128];

    float c = 0.0f, selh = 0.0f, selc = 0.0f;
    const f32x4 zero4 = {0.0f, 0.0f, 0.0f, 0.0f};

    for (int phase = 0; phase < 2; ++phase) {
        const float* tab  = phase ? tab2 : tab1;
        const float* Whh  = phase ? Whh2 : Whh1;
        const int*   sent = phase ? s2 : s1;
        const int*   lenp = phase ? len2 : len1;

        // stage tokens transposed (coalesced reads; one-time)
        for (int i = tid; i < 4 * Tt; i += 256)
            toklds[i & 255][i >> 8] = sent[(size_t)(b0 + (i >> 8)) * Tt + (i & 255)];

        // A fragments: m-tile k (gate type) covers gates 64k+16w+0..15
        b16x8 af[8];
#pragma unroll
        for (int k = 0; k < 4; ++k) {
            const int gate = 64 * k + 16 * w + mn;
#pragma unroll
            for (int kh = 0; kh < 2; ++kh) {
                const float* ar = Whh + (size_t)gate * Hh + kh * 32 + q * 8;
                const float4 f0 = *(const float4*)ar;
                const float4 f1 = *(const float4*)(ar + 4);
                b16x8 a;
                a[0] = (__bf16)f0.x; a[1] = (__bf16)f0.y;
                a[2] = (__bf16)f0.z; a[3] = (__bf16)f0.w;
                a[4] = (__bf16)f1.x; a[5] = (__bf16)f1.y;
                a[6] = (__bf16)f1.z; a[7] = (__bf16)f1.w;
                af[2 * k + kh] = a;
            }
        }

        const int mi = lenp[(size_t)(b0 + row) * Hh + u_own];

        // seed h/c (zeros phase 0, gathered state phase 1) into buffer 0
        const float h0f = phase ? selh : 0.0f;
        c = phase ? selc : 0.0f;
        hsh[0][row][u_own] = (__bf16)h0f;
        selh = 0.0f; selc = 0.0f;
        __syncthreads();

        // xw prefetch, distance 4: one float4 = all 4 gate xw of (token, u_own)
        const float* tu = tab + 4 * u_own;
        f32x4 Sa, Sb, Sc, Sd;
        auto prime = [&](int t, f32x4& S) {
            S = *(const f32x4*)(tu + (size_t)toklds[t][row] * 256);
        };
        prime(0, Sa); prime(1, Sb); prime(2, Sc); prime(3, Sd);

        // select acc element rsel (2-bit, runtime) with static element indices
        auto pick = [&](const f32x4& a) -> float {
            const float e01 = sb0 ? a[1] : a[0];
            const float e23 = sb0 ? a[3] : a[2];
            return sb1 ? e23 : e01;
        };

        auto step = [&](int t, f32x4& S, int rb, int wb) {
            // B frags: 4x column-duplicated rows (broadcast read = free)
            const b16x8 bf0 = *(const b16x8*)&hsh[rb][row][q * 8];
            const b16x8 bf1 = *(const b16x8*)&hsh[rb][row][32 + q * 8];
            // refill for t+4 issues NOW (address off LDS only) -- its issue no
            // longer waits on the MFMA results; consumed 4 steps from now
            const int tnext = (t + 4 < Tt) ? t + 4 : Tt - 1;
            const f32x4 Snew = *(const f32x4*)(tu + (size_t)toklds[tnext][row] * 256);

            // 8 INDEPENDENT MFMAs (zero-C): K-halves summed post-pick, so the
            // chain carries one MFMA latency, not two. Order g first (tanh).
            f32x4 aG0 = __builtin_amdgcn_mfma_f32_16x16x32_bf16(af[4], bf0, zero4, 0, 0, 0);
            f32x4 aG1 = __builtin_amdgcn_mfma_f32_16x16x32_bf16(af[5], bf1, zero4, 0, 0, 0);
            f32x4 aI0 = __builtin_amdgcn_mfma_f32_16x16x32_bf16(af[0], bf0, zero4, 0, 0, 0);
            f32x4 aI1 = __builtin_amdgcn_mfma_f32_16x16x32_bf16(af[1], bf1, zero4, 0, 0, 0);
            f32x4 aF0 = __builtin_amdgcn_mfma_f32_16x16x32_bf16(af[2], bf0, zero4, 0, 0, 0);
            f32x4 aF1 = __builtin_amdgcn_mfma_f32_16x16x32_bf16(af[3], bf1, zero4, 0, 0, 0);
            f32x4 aO0 = __builtin_amdgcn_mfma_f32_16x16x32_bf16(af[6], bf0, zero4, 0, 0, 0);
            f32x4 aO1 = __builtin_amdgcn_mfma_f32_16x16x32_bf16(af[7], bf1, zero4, 0, 0, 0);

            const float gG = pick(aG0) + pick(aG1) + S[2];
            const float gI = pick(aI0) + pick(aI1) + S[0];
            const float gF = pick(aF0) + pick(aF1) + S[1];
            const float gO = pick(aO0) + pick(aO1) + S[3];
            S = Snew;   // rotate prefetch register

            const float gv = ftanh(gG);
            const float iv = fsig(gI);
            const float fv = fsig(gF);
            const float ov = fsig(gO);
            c = fv * c + iv * gv;
            const float hv = ov * ftanh(c);
            hsh[wb][row][u_own] = (__bf16)hv;
            if (t == mi) { selh = hv; selc = c; }
            barrier_novm();   // ONE barrier/step; global prefetch stays in flight
        };

        for (int t = 0; t < Tt; t += 4) {
            step(t,     Sa, 0, 1);
            step(t + 1, Sb, 1, 0);
            step(t + 2, Sc, 0, 1);
            step(t + 3, Sd, 1, 0);
        }
    }

    // ---------------- epilogue MLP on the 4 gathered rows -------------------
    h2s[row][u_own] = selh;
    __syncthreads();
#pragma unroll
    for (int p = 0; p < 2; ++p) {
        const int idx = tid + 256 * p;        // 512 (row, neuron) tasks
        const int rr = idx >> 7, n = idx & 127;
        float a = bl1[n];
        const float* wl = Wl1 + n * 64;
#pragma unroll 8
        for (int k = 0; k < 64; ++k) a += h2s[rr][k] * wl[k];
        ys[rr][n] = ftanh(a);
    }
    __syncthreads();
    if (tid < 16) {
        const int rr = tid >> 2, o = tid & 3;
        float a = bl2[o];
        const float* wl = Wl2 + o * 128;
#pragma unroll 8
        for (int k = 0; k < 128; ++k) a += ys[rr][k] * wl[k];
        out[(size_t)(b0 + rr) * 4 + o] = a;
    }
}

// ---------------------------------------------------------------------------
extern "C" void kernel_launch(void* const* d_in, const int* in_sizes, int n_in,
                              void* d_out, int out_size, void* d_ws, size_t ws_size,
                              hipStream_t stream) {
    const int*   s1   = (const int*)d_in[0];
    const int*   s2   = (const int*)d_in[1];
    const int*   l1   = (const int*)d_in[2];
    const int*   l2   = (const int*)d_in[3];
    // d_in[4], d_in[5] (s1_s, s2_s) unused by the reference
    const float* emb  = (const float*)d_in[6];
    const float* Wih1 = (const float*)d_in[7];
    const float* Whh1 = (const float*)d_in[8];
    const float* bih1 = (const float*)d_in[9];
    const float* bhh1 = (const float*)d_in[10];
    const float* Wih2 = (const float*)d_in[11];
    const float* Whh2 = (const float*)d_in[12];
    const float* bih2 = (const float*)d_in[13];
    const float* bhh2 = (const float*)d_in[14];
    const float* Wl1  = (const float*)d_in[15];
    const float* bl1  = (const float*)d_in[16];
    const float* Wl2  = (const float*)d_in[17];
    const float* bl2  = (const float*)d_in[18];
    float* out = (float*)d_out;

    float* tab1 = (float*)d_ws;                       // [V,256] fp32, unit-major
    float* tab2 = tab1 + (size_t)Vv * 256;            // [V,256] fp32  (65.6 MB)

    dim3 grid((Vv + MB - 1) / MB, 2);
    build_tables<<<grid, 256, 0, stream>>>(emb, Wih1, bih1, bhh1,
                                           Wih2, bih2, bhh2, tab1, tab2);
    lstm_main<<<Bsz / 4, 256, 0, stream>>>(s1, s2, l1, l2, tab1, tab2,
                                           Whh1, Whh2, Wl1, bl1, Wl2, bl2, out);
}

// Round 7
// 281.543 us; speedup vs baseline: 1.0901x; 1.0901x over previous
//
#include <hip/hip_runtime.h>

#define Bsz 1024
#define Tt  256
#define Vv  32004
#define Dd  50
#define Hh  64
#define MB  128  // vocab rows per build_tables block

typedef __bf16 b16x8 __attribute__((ext_vector_type(8)));
typedef float  f32x4 __attribute__((ext_vector_type(4)));

// barrier WITHOUT vmcnt(0) drain: LDS ordering only, in-flight global loads
// (the xw register prefetch) survive across it.
__device__ __forceinline__ void barrier_novm() {
    asm volatile("s_waitcnt lgkmcnt(0)\n\ts_barrier" ::: "memory");
}
// Fast activations via raw gfx950 opcodes: v_exp_f32 = 2^x, v_rcp_f32 = 1/x.
// (Verified win round 5: lstm 236 -> 190 us vs IEEE div sequences.)
__device__ __forceinline__ float fexp2(float x) {
    float r;
    asm("v_exp_f32 %0, %1" : "=v"(r) : "v"(x));
    return r;
}
__device__ __forceinline__ float frcp(float x) {
    float r;
    asm("v_rcp_f32 %0, %1" : "=v"(r) : "v"(x));
    return r;
}
__device__ __forceinline__ float fsig(float x) {
    return frcp(1.0f + fexp2(x * -1.442695041f));                // 1/(1+e^-x)
}
__device__ __forceinline__ float ftanh(float x) {
    return 2.0f * frcp(1.0f + fexp2(x * -2.885390082f)) - 1.0f;  // 2/(1+e^-2x)-1
}

// fp32 -> bf16 hi/lo split (3-term product keeps ~fp32 accuracy)
__device__ __forceinline__ void cvt_hilo(const float* x, b16x8& hi, b16x8& lo) {
#pragma unroll
    for (int e = 0; e < 8; ++e) {
        const __bf16 h = (__bf16)x[e];
        hi[e] = h;
        lo[e] = (__bf16)(x[e] - (float)h);
    }
}

// ---------------------------------------------------------------------------
// Prologue (r6 form, kept): tab[v][unit*4+gate] = emb[v,:].Wih[g,:] + bias.
// First-principles cost ~10us; the stubborn ~93us "rest" across 4 different
// build implementations decomposes as ~84us fixed harness overhead + build.
// ---------------------------------------------------------------------------
__launch_bounds__(256)
__global__ void build_tables(const float* __restrict__ emb,
                             const float* __restrict__ Wih1,
                             const float* __restrict__ bih1,
                             const float* __restrict__ bhh1,
                             const float* __restrict__ Wih2,
                             const float* __restrict__ bih2,
                             const float* __restrict__ bhh2,
                             float* __restrict__ tab1,
                             float* __restrict__ tab2) {
    const int tid  = threadIdx.x;
    const int w    = tid >> 6;        // wave: unit tile 16w..16w+15
    const int lane = tid & 63;
    const int q    = lane >> 4;
    const int mn   = lane & 15;
    const int v0   = blockIdx.x * MB;

    const float* Wih = blockIdx.y ? Wih2 : Wih1;
    const float* bih = blockIdx.y ? bih2 : bih1;
    const float* bhh = blockIdx.y ? bhh2 : bhh1;
    float*       tab = blockIdx.y ? tab2 : tab1;

    __shared__ __align__(16) float wlds[256 * Dd];   // 51.2 KB, flat row-major
    __shared__ __align__(16) float elds[MB * Dd];    // 25.6 KB, flat row-major

    // flat coalesced staging: Wih = 12800 dwords = 3200 float4
    for (int d4 = tid; d4 < 256 * Dd / 4; d4 += 256)
        *(float4*)&wlds[4 * d4] = *(const float4*)(Wih + 4 * d4);
    // emb tile: 6400 dwords = 1600 float4, clamped at the vocab end
    {
        const int ebase = v0 * Dd;
        const int elim  = Vv * Dd - ebase;   // valid dwords from ebase
        const int mx    = Vv * Dd - 1;
        for (int d4 = tid; d4 < MB * Dd / 4; d4 += 256) {
            const int d = 4 * d4;
            float4 v;
            if (d + 4 <= elim) {
                v = *(const float4*)(emb + ebase + d);
            } else {
                v.x = emb[min(ebase + d,     mx)];
                v.y = emb[min(ebase + d + 1, mx)];
                v.z = emb[min(ebase + d + 2, mx)];
                v.w = emb[min(ebase + d + 3, mx)];
            }
            *(float4*)&elds[d] = v;
        }
    }
    __syncthreads();

    // B fragments (Wih^T) from LDS, gate-type k: B[kd=8q+j][n=mn]
    b16x8 bh[4][2], bl[4][2];
    f32x4 bias4;
#pragma unroll
    for (int k = 0; k < 4; ++k) {
        const int g = 64 * k + 16 * w + mn;
        const int base = g * Dd;
        float x[8];
#pragma unroll
        for (int j = 0; j < 8; ++j) x[j] = wlds[base + 8 * q + j];   // cols<32
        cvt_hilo(x, bh[k][0], bl[k][0]);
#pragma unroll
        for (int j = 0; j < 8; ++j) {
            const int col = 32 + 8 * q + j;
            x[j] = (col < Dd) ? wlds[base + col] : 0.0f;
        }
        cvt_hilo(x, bh[k][1], bl[k][1]);
        bias4[k] = bih[g] + bhh[g];
    }

#pragma unroll 1
    for (int m = 0; m < MB / 16; ++m) {
        // A fragment from LDS: A[mr=mn][kd] = emb[v0+16m+mn][kd]
        const int base = (16 * m + mn) * Dd;
        b16x8 ah[2], al[2];
        float x[8];
#pragma unroll
        for (int j = 0; j < 8; ++j) x[j] = elds[base + 8 * q + j];
        cvt_hilo(x, ah[0], al[0]);
#pragma unroll
        for (int j = 0; j < 8; ++j) {
            const int col = 32 + 8 * q + j;
            x[j] = (col < Dd) ? elds[base + col] : 0.0f;
        }
        cvt_hilo(x, ah[1], al[1]);

        f32x4 acc[4];
#pragma unroll
        for (int k = 0; k < 4; ++k) {
            f32x4 a = {0.0f, 0.0f, 0.0f, 0.0f};
#pragma unroll
            for (int kh = 0; kh < 2; ++kh) {
                a = __builtin_amdgcn_mfma_f32_16x16x32_bf16(ah[kh], bh[k][kh], a, 0, 0, 0);
                a = __builtin_amdgcn_mfma_f32_16x16x32_bf16(ah[kh], bl[k][kh], a, 0, 0, 0);
                a = __builtin_amdgcn_mfma_f32_16x16x32_bf16(al[kh], bh[k][kh], a, 0, 0, 0);
            }
            acc[k] = a;
        }
        // store: one contiguous float4 {i,f,g,o}+bias per (lane, r)
#pragma unroll
        for (int r = 0; r < 4; ++r) {
            const int vr = v0 + 16 * m + 4 * q + r;
            if (vr < Vv) {
                f32x4 o;
                o[0] = acc[0][r] + bias4[0];
                o[1] = acc[1][r] + bias4[1];
                o[2] = acc[2][r] + bias4[2];
                o[3] = acc[3][r] + bias4[3];
                *(f32x4*)(tab + (size_t)vr * 256 + (16 * w + mn) * 4) = o;
            }
        }
    }
}

// ---------------------------------------------------------------------------
// v7 recurrence == v5 (the 190.7us kernel), restored verbatim after v6's
// regression. Root cause of v6: rotating the prefetch through a temp
// (S = Snew) forces the vmcnt wait for the t+4 load INSIDE step t --
// prefetch distance collapsed 4 -> ~0.5 and every step ate exposed HBM
// latency. v5's in-place WAR refill (S reloaded AFTER its consumption)
// defers the wait 4 steps. Chained MFMA pairs also restored (v6's
// independent pairs added +16 VALU of picks). Only change vs v5: h ds_write
// issued before the sel cndmasks (write off the critical tail).
// ---------------------------------------------------------------------------
__launch_bounds__(256, 1)
__global__ void lstm_main(const int*   __restrict__ s1,
                          const int*   __restrict__ s2,
                          const int*   __restrict__ len1,
                          const int*   __restrict__ len2,
                          const float* __restrict__ tab1,
                          const float* __restrict__ tab2,
                          const float* __restrict__ Whh1,
                          const float* __restrict__ Whh2,
                          const float* __restrict__ Wl1,
                          const float* __restrict__ bl1,
                          const float* __restrict__ Wl2,
                          const float* __restrict__ bl2,
                          float* __restrict__ out) {
    const int tid  = threadIdx.x;
    const int w    = tid >> 6;        // wave: unit tile [16w,16w+16)
    const int lane = tid & 63;
    const int q    = lane >> 4;       // MFMA quad
    const int mn   = lane & 15;       // B/C column
    const int row  = mn & 3;          // batch row within block
    const bool sb0 = (mn >> 2) & 1;   // rsel bit0
    const bool sb1 = (mn >> 3) & 1;   // rsel bit1
    const int u_own = 16 * w + 4 * q + (mn >> 2);  // this lane's hidden unit
    const int b0   = blockIdx.x * 4;

    __shared__ __align__(16) __bf16 hsh[2][4][96];  // row stride 192B: 2-way banks
    __shared__ int   toklds[Tt][4];                 // transposed: uniform-t read
    __shared__ float h2s[4][64];
    __shared__ float ys[4][128];

    float c = 0.0f, selh = 0.0f, selc = 0.0f;
    const f32x4 zero4 = {0.0f, 0.0f, 0.0f, 0.0f};

    for (int phase = 0; phase < 2; ++phase) {
        const float* tab  = phase ? tab2 : tab1;
        const float* Whh  = phase ? Whh2 : Whh1;
        const int*   sent = phase ? s2 : s1;
        const int*   lenp = phase ? len2 : len1;

        // stage tokens transposed (coalesced reads; one-time)
        for (int i = tid; i < 4 * Tt; i += 256)
            toklds[i & 255][i >> 8] = sent[(size_t)(b0 + (i >> 8)) * Tt + (i & 255)];

        // A fragments: m-tile k (gate type) covers gates 64k+16w+0..15
        b16x8 af[8];
#pragma unroll
        for (int k = 0; k < 4; ++k) {
            const int gate = 64 * k + 16 * w + mn;
#pragma unroll
            for (int kh = 0; kh < 2; ++kh) {
                const float* ar = Whh + (size_t)gate * Hh + kh * 32 + q * 8;
                const float4 f0 = *(const float4*)ar;
                const float4 f1 = *(const float4*)(ar + 4);
                b16x8 a;
                a[0] = (__bf16)f0.x; a[1] = (__bf16)f0.y;
                a[2] = (__bf16)f0.z; a[3] = (__bf16)f0.w;
                a[4] = (__bf16)f1.x; a[5] = (__bf16)f1.y;
                a[6] = (__bf16)f1.z; a[7] = (__bf16)f1.w;
                af[2 * k + kh] = a;
            }
        }

        const int mi = lenp[(size_t)(b0 + row) * Hh + u_own];

        // seed h/c (zeros phase 0, gathered state phase 1) into buffer 0
        const float h0f = phase ? selh : 0.0f;
        c = phase ? selc : 0.0f;
        hsh[0][row][u_own] = (__bf16)h0f;
        selh = 0.0f; selc = 0.0f;
        __syncthreads();

        // xw prefetch, distance 4: one float4 = all 4 gate xw of (token, u_own)
        const float* tu = tab + 4 * u_own;
        f32x4 Sa, Sb, Sc, Sd;
        auto prime = [&](int t, f32x4& S) {
            S = *(const f32x4*)(tu + (size_t)toklds[t][row] * 256);
        };
        prime(0, Sa); prime(1, Sb); prime(2, Sc); prime(3, Sd);

        // select acc element rsel (2-bit, runtime) with static element indices
        auto pick = [&](const f32x4& a) -> float {
            const float e01 = sb0 ? a[1] : a[0];
            const float e23 = sb0 ? a[3] : a[2];
            return sb1 ? e23 : e01;
        };

        auto step = [&](int t, f32x4& S, int rb, int wb) {
            // B frags: 4x column-duplicated rows (broadcast read = free)
            const b16x8 bf0 = *(const b16x8*)&hsh[rb][row][q * 8];
            const b16x8 bf1 = *(const b16x8*)&hsh[rb][row][32 + q * 8];
            const int tnext = (t + 4 < Tt) ? t + 4 : Tt - 1;
            const int tk = toklds[tnext][row];

            // order g,i,f,o: tanh(gG) is the longest dependent chain
            f32x4 aG = __builtin_amdgcn_mfma_f32_16x16x32_bf16(af[4], bf0, zero4, 0, 0, 0);
            aG = __builtin_amdgcn_mfma_f32_16x16x32_bf16(af[5], bf1, aG, 0, 0, 0);
            f32x4 aI = __builtin_amdgcn_mfma_f32_16x16x32_bf16(af[0], bf0, zero4, 0, 0, 0);
            aI = __builtin_amdgcn_mfma_f32_16x16x32_bf16(af[1], bf1, aI, 0, 0, 0);
            f32x4 aF = __builtin_amdgcn_mfma_f32_16x16x32_bf16(af[2], bf0, zero4, 0, 0, 0);
            aF = __builtin_amdgcn_mfma_f32_16x16x32_bf16(af[3], bf1, aF, 0, 0, 0);
            f32x4 aO = __builtin_amdgcn_mfma_f32_16x16x32_bf16(af[6], bf0, zero4, 0, 0, 0);
            aO = __builtin_amdgcn_mfma_f32_16x16x32_bf16(af[7], bf1, aO, 0, 0, 0);

            const float gG = pick(aG) + S[2];
            const float gI = pick(aI) + S[0];
            const float gF = pick(aF) + S[1];
            const float gO = pick(aO) + S[3];
            // refill S for t+4 IN PLACE (WAR): issue after the consuming adds,
            // vmcnt wait deferred to S's use 4 steps out = full distance-4
            S = *(const f32x4*)(tu + (size_t)tk * 256);

            const float gv = ftanh(gG);
            const float iv = fsig(gI);
            const float fv = fsig(gF);
            const float ov = fsig(gO);
            c = fv * c + iv * gv;
            const float hv = ov * ftanh(c);
            hsh[wb][row][u_own] = (__bf16)hv;   // write first: off the tail
            if (t == mi) { selh = hv; selc = c; }
            barrier_novm();   // ONE barrier/step; global prefetch stays in flight
        };

        for (int t = 0; t < Tt; t += 4) {
            step(t,     Sa, 0, 1);
            step(t + 1, Sb, 1, 0);
            step(t + 2, Sc, 0, 1);
            step(t + 3, Sd, 1, 0);
        }
    }

    // ---------------- epilogue MLP on the 4 gathered rows -------------------
    h2s[row][u_own] = selh;
    __syncthreads();
#pragma unroll
    for (int p = 0; p < 2; ++p) {
        const int idx = tid + 256 * p;        // 512 (row, neuron) tasks
        const int rr = idx >> 7, n = idx & 127;
        float a = bl1[n];
        const float* wl = Wl1 + n * 64;
#pragma unroll 8
        for (int k = 0; k < 64; ++k) a += h2s[rr][k] * wl[k];
        ys[rr][n] = ftanh(a);
    }
    __syncthreads();
    if (tid < 16) {
        const int rr = tid >> 2, o = tid & 3;
        float a = bl2[o];
        const float* wl = Wl2 + o * 128;
#pragma unroll 8
        for (int k = 0; k < 128; ++k) a += ys[rr][k] * wl[k];
        out[(size_t)(b0 + rr) * 4 + o] = a;
    }
}

// ---------------------------------------------------------------------------
extern "C" void kernel_launch(void* const* d_in, const int* in_sizes, int n_in,
                              void* d_out, int out_size, void* d_ws, size_t ws_size,
                              hipStream_t stream) {
    const int*   s1   = (const int*)d_in[0];
    const int*   s2   = (const int*)d_in[1];
    const int*   l1   = (const int*)d_in[2];
    const int*   l2   = (const int*)d_in[3];
    // d_in[4], d_in[5] (s1_s, s2_s) unused by the reference
    const float* emb  = (const float*)d_in[6];
    const float* Wih1 = (const float*)d_in[7];
    const float* Whh1 = (const float*)d_in[8];
    const float* bih1 = (const float*)d_in[9];
    const float* bhh1 = (const float*)d_in[10];
    const float* Wih2 = (const float*)d_in[11];
    const float* Whh2 = (const float*)d_in[12];
    const float* bih2 = (const float*)d_in[13];
    const float* bhh2 = (const float*)d_in[14];
    const float* Wl1  = (const float*)d_in[15];
    const float* bl1  = (const float*)d_in[16];
    const float* Wl2  = (const float*)d_in[17];
    const float* bl2  = (const float*)d_in[18];
    float* out = (float*)d_out;

    float* tab1 = (float*)d_ws;                       // [V,256] fp32, unit-major
    float* tab2 = tab1 + (size_t)Vv * 256;            // [V,256] fp32  (65.6 MB)

    dim3 grid((Vv + MB - 1) / MB, 2);
    build_tables<<<grid, 256, 0, stream>>>(emb, Wih1, bih1, bhh1,
                                           Wih2, bih2, bhh2, tab1, tab2);
    lstm_main<<<Bsz / 4, 256, 0, stream>>>(s1, s2, l1, l2, tab1, tab2,
                                           Whh1, Whh2, Wl1, bl1, Wl2, bl2, out);
}

// Round 8
// 259.699 us; speedup vs baseline: 1.1818x; 1.0841x over previous
//
#include <hip/hip_runtime.h>

#define Bsz 1024
#define Tt  256
#define Vv  32004
#define Dd  50
#define Hh  64
#define MB  128  // vocab rows per build_tables block

typedef __bf16 b16x8 __attribute__((ext_vector_type(8)));
typedef float  f32x4 __attribute__((ext_vector_type(4)));

// barrier WITHOUT vmcnt(0) drain: LDS ordering only, in-flight global loads
// (the xw register prefetch) survive across it.
__device__ __forceinline__ void barrier_novm() {
    asm volatile("s_waitcnt lgkmcnt(0)\n\ts_barrier" ::: "memory");
}
// Fast activations via raw gfx950 opcodes: v_exp_f32 = 2^x, v_rcp_f32 = 1/x.
// (Verified win round 5: lstm 236 -> 190 us vs IEEE div sequences.)
__device__ __forceinline__ float fexp2(float x) {
    float r;
    asm("v_exp_f32 %0, %1" : "=v"(r) : "v"(x));
    return r;
}
__device__ __forceinline__ float frcp(float x) {
    float r;
    asm("v_rcp_f32 %0, %1" : "=v"(r) : "v"(x));
    return r;
}
__device__ __forceinline__ float fsig(float x) {
    return frcp(1.0f + fexp2(x * -1.442695041f));                // 1/(1+e^-x)
}
__device__ __forceinline__ float ftanh(float x) {
    return 2.0f * frcp(1.0f + fexp2(x * -2.885390082f)) - 1.0f;  // 2/(1+e^-2x)-1
}

// fp32 -> bf16 hi/lo split (3-term product keeps ~fp32 accuracy)
__device__ __forceinline__ void cvt_hilo(const float* x, b16x8& hi, b16x8& lo) {
#pragma unroll
    for (int e = 0; e < 8; ++e) {
        const __bf16 h = (__bf16)x[e];
        hi[e] = h;
        lo[e] = (__bf16)(x[e] - (float)h);
    }
}

// ---------------------------------------------------------------------------
// Prologue (r6 form, kept): tab[v][unit*4+gate] = emb[v,:].Wih[g,:] + bias.
// First-principles cost ~10us; the stubborn ~93us "rest" across 5 different
// build implementations decomposes as ~84us fixed harness overhead + build.
// ---------------------------------------------------------------------------
__launch_bounds__(256)
__global__ void build_tables(const float* __restrict__ emb,
                             const float* __restrict__ Wih1,
                             const float* __restrict__ bih1,
                             const float* __restrict__ bhh1,
                             const float* __restrict__ Wih2,
                             const float* __restrict__ bih2,
                             const float* __restrict__ bhh2,
                             float* __restrict__ tab1,
                             float* __restrict__ tab2) {
    const int tid  = threadIdx.x;
    const int w    = tid >> 6;        // wave: unit tile 16w..16w+15
    const int lane = tid & 63;
    const int q    = lane >> 4;
    const int mn   = lane & 15;
    const int v0   = blockIdx.x * MB;

    const float* Wih = blockIdx.y ? Wih2 : Wih1;
    const float* bih = blockIdx.y ? bih2 : bih1;
    const float* bhh = blockIdx.y ? bhh2 : bhh1;
    float*       tab = blockIdx.y ? tab2 : tab1;

    __shared__ __align__(16) float wlds[256 * Dd];   // 51.2 KB, flat row-major
    __shared__ __align__(16) float elds[MB * Dd];    // 25.6 KB, flat row-major

    // flat coalesced staging: Wih = 12800 dwords = 3200 float4
    for (int d4 = tid; d4 < 256 * Dd / 4; d4 += 256)
        *(float4*)&wlds[4 * d4] = *(const float4*)(Wih + 4 * d4);
    // emb tile: 6400 dwords = 1600 float4, clamped at the vocab end
    {
        const int ebase = v0 * Dd;
        const int elim  = Vv * Dd - ebase;   // valid dwords from ebase
        const int mx    = Vv * Dd - 1;
        for (int d4 = tid; d4 < MB * Dd / 4; d4 += 256) {
            const int d = 4 * d4;
            float4 v;
            if (d + 4 <= elim) {
                v = *(const float4*)(emb + ebase + d);
            } else {
                v.x = emb[min(ebase + d,     mx)];
                v.y = emb[min(ebase + d + 1, mx)];
                v.z = emb[min(ebase + d + 2, mx)];
                v.w = emb[min(ebase + d + 3, mx)];
            }
            *(float4*)&elds[d] = v;
        }
    }
    __syncthreads();

    // B fragments (Wih^T) from LDS, gate-type k: B[kd=8q+j][n=mn]
    b16x8 bh[4][2], bl[4][2];
    f32x4 bias4;
#pragma unroll
    for (int k = 0; k < 4; ++k) {
        const int g = 64 * k + 16 * w + mn;
        const int base = g * Dd;
        float x[8];
#pragma unroll
        for (int j = 0; j < 8; ++j) x[j] = wlds[base + 8 * q + j];   // cols<32
        cvt_hilo(x, bh[k][0], bl[k][0]);
#pragma unroll
        for (int j = 0; j < 8; ++j) {
            const int col = 32 + 8 * q + j;
            x[j] = (col < Dd) ? wlds[base + col] : 0.0f;
        }
        cvt_hilo(x, bh[k][1], bl[k][1]);
        bias4[k] = bih[g] + bhh[g];
    }

#pragma unroll 1
    for (int m = 0; m < MB / 16; ++m) {
        // A fragment from LDS: A[mr=mn][kd] = emb[v0+16m+mn][kd]
        const int base = (16 * m + mn) * Dd;
        b16x8 ah[2], al[2];
        float x[8];
#pragma unroll
        for (int j = 0; j < 8; ++j) x[j] = elds[base + 8 * q + j];
        cvt_hilo(x, ah[0], al[0]);
#pragma unroll
        for (int j = 0; j < 8; ++j) {
            const int col = 32 + 8 * q + j;
            x[j] = (col < Dd) ? elds[base + col] : 0.0f;
        }
        cvt_hilo(x, ah[1], al[1]);

        f32x4 acc[4];
#pragma unroll
        for (int k = 0; k < 4; ++k) {
            f32x4 a = {0.0f, 0.0f, 0.0f, 0.0f};
#pragma unroll
            for (int kh = 0; kh < 2; ++kh) {
                a = __builtin_amdgcn_mfma_f32_16x16x32_bf16(ah[kh], bh[k][kh], a, 0, 0, 0);
                a = __builtin_amdgcn_mfma_f32_16x16x32_bf16(ah[kh], bl[k][kh], a, 0, 0, 0);
                a = __builtin_amdgcn_mfma_f32_16x16x32_bf16(al[kh], bh[k][kh], a, 0, 0, 0);
            }
            acc[k] = a;
        }
        // store: one contiguous float4 {i,f,g,o}+bias per (lane, r)
#pragma unroll
        for (int r = 0; r < 4; ++r) {
            const int vr = v0 + 16 * m + 4 * q + r;
            if (vr < Vv) {
                f32x4 o;
                o[0] = acc[0][r] + bias4[0];
                o[1] = acc[1][r] + bias4[1];
                o[2] = acc[2][r] + bias4[2];
                o[3] = acc[3][r] + bias4[3];
                *(f32x4*)(tab + (size_t)vr * 256 + (16 * w + mn) * 4) = o;
            }
        }
    }
}

// ---------------------------------------------------------------------------
// v8 recurrence: v7 structure (256 blocks x 4 rows, 4 waves, in-register
// gates, 1 novm-barrier/step) with the step's off-chain work moved off the
// critical path:
//  - tokens prefetched into REGISTERS as int4 chunks (1 ds_read_b128 per 4
//    steps per lane from per-row-contiguous toklds[4][Tt+8], +8 dword row pad
//    spreads the 4 row-addresses across banks) -- removes the per-step
//    ds_read_b32 and its dependent S-address chain (4 fewer LDS ops/step/CU).
//  - 8-slot S rotation: step i consumes S[i], refills S[(i+4)&7] (idle for 4
//    steps, so NO same-step WAR). The refill has zero dependence on this
//    step's compute -> the global load issues at cycle 0 of the step while
//    keeping v7's distance-4 coverage (v6's collapse is avoided: the consumed
//    slot is untouched). All slots are named registers (rule #20).
// ---------------------------------------------------------------------------
__launch_bounds__(256, 1)
__global__ void lstm_main(const int*   __restrict__ s1,
                          const int*   __restrict__ s2,
                          const int*   __restrict__ len1,
                          const int*   __restrict__ len2,
                          const float* __restrict__ tab1,
                          const float* __restrict__ tab2,
                          const float* __restrict__ Whh1,
                          const float* __restrict__ Whh2,
                          const float* __restrict__ Wl1,
                          const float* __restrict__ bl1,
                          const float* __restrict__ Wl2,
                          const float* __restrict__ bl2,
                          float* __restrict__ out) {
    const int tid  = threadIdx.x;
    const int w    = tid >> 6;        // wave: unit tile [16w,16w+16)
    const int lane = tid & 63;
    const int q    = lane >> 4;       // MFMA quad
    const int mn   = lane & 15;       // B/C column
    const int row  = mn & 3;          // batch row within block
    const bool sb0 = (mn >> 2) & 1;   // rsel bit0
    const bool sb1 = (mn >> 3) & 1;   // rsel bit1
    const int u_own = 16 * w + 4 * q + (mn >> 2);  // this lane's hidden unit
    const int b0   = blockIdx.x * 4;

    __shared__ __align__(16) __bf16 hsh[2][4][96];  // row stride 192B: 2-way banks
    __shared__ __align__(16) int toklds[4][Tt + 8]; // per-row contiguous, padded
    __shared__ float h2s[4][64];
    __shared__ float ys[4][128];

    float c = 0.0f, selh = 0.0f, selc = 0.0f;
    const f32x4 zero4 = {0.0f, 0.0f, 0.0f, 0.0f};

    for (int phase = 0; phase < 2; ++phase) {
        const float* tab  = phase ? tab2 : tab1;
        const float* Whh  = phase ? Whh2 : Whh1;
        const int*   sent = phase ? s2 : s1;
        const int*   lenp = phase ? len2 : len1;

        // stage tokens per-row contiguous (coalesced over t; one-time)
        for (int i = tid; i < 4 * Tt; i += 256)
            toklds[i >> 8][i & 255] = sent[(size_t)(b0 + (i >> 8)) * Tt + (i & 255)];

        // A fragments: m-tile k (gate type) covers gates 64k+16w+0..15
        b16x8 af[8];
#pragma unroll
        for (int k = 0; k < 4; ++k) {
            const int gate = 64 * k + 16 * w + mn;
#pragma unroll
            for (int kh = 0; kh < 2; ++kh) {
                const float* ar = Whh + (size_t)gate * Hh + kh * 32 + q * 8;
                const float4 f0 = *(const float4*)ar;
                const float4 f1 = *(const float4*)(ar + 4);
                b16x8 a;
                a[0] = (__bf16)f0.x; a[1] = (__bf16)f0.y;
                a[2] = (__bf16)f0.z; a[3] = (__bf16)f0.w;
                a[4] = (__bf16)f1.x; a[5] = (__bf16)f1.y;
                a[6] = (__bf16)f1.z; a[7] = (__bf16)f1.w;
                af[2 * k + kh] = a;
            }
        }

        const int mi = lenp[(size_t)(b0 + row) * Hh + u_own];

        // seed h/c (zeros phase 0, gathered state phase 1) into buffer 0
        const float h0f = phase ? selh : 0.0f;
        c = phase ? selc : 0.0f;
        hsh[0][row][u_own] = (__bf16)h0f;
        selh = 0.0f; selc = 0.0f;
        __syncthreads();

        const float* tu = tab + 4 * u_own;

        // token register chunks: tkA = tokens[tb+4..7], tkB = tokens[tb+8..11]
        int4 tk0 = *(const int4*)&toklds[row][0];
        int4 tkA = *(const int4*)&toklds[row][4];
        int4 tkB = *(const int4*)&toklds[row][8];

        // prime S slots 0..3 (t=0..3); slots 4..7 are filled during steps 0..3
        f32x4 S0, S1, S2, S3, S4, S5, S6, S7;
        S0 = *(const f32x4*)(tu + (size_t)tk0.x * 256);
        S1 = *(const f32x4*)(tu + (size_t)tk0.y * 256);
        S2 = *(const f32x4*)(tu + (size_t)tk0.z * 256);
        S3 = *(const f32x4*)(tu + (size_t)tk0.w * 256);

        // select acc element rsel (2-bit, runtime) with static element indices
        auto pick = [&](const f32x4& a) -> float {
            const float e01 = sb0 ? a[1] : a[0];
            const float e23 = sb0 ? a[3] : a[2];
            return sb1 ? e23 : e01;
        };

        // step i: consume Su (slot i), refill Sf (slot (i+4)&7) with token tok
        auto step = [&](int i, f32x4& Su, f32x4& Sf, int tok, int tb) {
            // refill FIRST: register token -> address ready, no compute dep,
            // load issues at step start; consumed slot Su untouched.
            Sf = *(const f32x4*)(tu + (size_t)tok * 256);

            const int rb = i & 1, wb = rb ^ 1;
            const b16x8 bf0 = *(const b16x8*)&hsh[rb][row][q * 8];
            const b16x8 bf1 = *(const b16x8*)&hsh[rb][row][32 + q * 8];

            // order g,i,f,o: tanh(gG) is the longest dependent chain
            f32x4 aG = __builtin_amdgcn_mfma_f32_16x16x32_bf16(af[4], bf0, zero4, 0, 0, 0);
            aG = __builtin_amdgcn_mfma_f32_16x16x32_bf16(af[5], bf1, aG, 0, 0, 0);
            f32x4 aI = __builtin_amdgcn_mfma_f32_16x16x32_bf16(af[0], bf0, zero4, 0, 0, 0);
            aI = __builtin_amdgcn_mfma_f32_16x16x32_bf16(af[1], bf1, aI, 0, 0, 0);
            f32x4 aF = __builtin_amdgcn_mfma_f32_16x16x32_bf16(af[2], bf0, zero4, 0, 0, 0);
            aF = __builtin_amdgcn_mfma_f32_16x16x32_bf16(af[3], bf1, aF, 0, 0, 0);
            f32x4 aO = __builtin_amdgcn_mfma_f32_16x16x32_bf16(af[6], bf0, zero4, 0, 0, 0);
            aO = __builtin_amdgcn_mfma_f32_16x16x32_bf16(af[7], bf1, aO, 0, 0, 0);

            const float gG = pick(aG) + Su[2];
            const float gI = pick(aI) + Su[0];
            const float gF = pick(aF) + Su[1];
            const float gO = pick(aO) + Su[3];

            const float gv = ftanh(gG);
            const float iv = fsig(gI);
            const float fv = fsig(gF);
            const float ov = fsig(gO);
            c = fv * c + iv * gv;
            const float hv = ov * ftanh(c);
            hsh[wb][row][u_own] = (__bf16)hv;   // write first: off the tail
            if (tb + i == mi) { selh = hv; selc = c; }
            barrier_novm();   // ONE barrier/step; global prefetch stays in flight
        };

        for (int tb = 0; tb < Tt; tb += 8) {
            step(0, S0, S4, tkA.x, tb);
            step(1, S1, S5, tkA.y, tb);
            // next-iteration token chunks (ds_read latency hidden under steps)
            const int nb1 = min(tb + 12, Tt - 4);
            const int4 tA2 = *(const int4*)&toklds[row][nb1];
            step(2, S2, S6, tkA.z, tb);
            const int nb2 = min(tb + 16, Tt - 4);
            const int4 tB2 = *(const int4*)&toklds[row][nb2];
            step(3, S3, S7, tkA.w, tb);
            step(4, S4, S0, tkB.x, tb);
            step(5, S5, S1, tkB.y, tb);
            step(6, S6, S2, tkB.z, tb);
            step(7, S7, S3, tkB.w, tb);
            tkA = tA2; tkB = tB2;
        }
    }

    // ---------------- epilogue MLP on the 4 gathered rows -------------------
    h2s[row][u_own] = selh;
    __syncthreads();
#pragma unroll
    for (int p = 0; p < 2; ++p) {
        const int idx = tid + 256 * p;        // 512 (row, neuron) tasks
        const int rr = idx >> 7, n = idx & 127;
        float a = bl1[n];
        const float* wl = Wl1 + n * 64;
#pragma unroll 8
        for (int k = 0; k < 64; ++k) a += h2s[rr][k] * wl[k];
        ys[rr][n] = ftanh(a);
    }
    __syncthreads();
    if (tid < 16) {
        const int rr = tid >> 2, o = tid & 3;
        float a = bl2[o];
        const float* wl = Wl2 + o * 128;
#pragma unroll 8
        for (int k = 0; k < 128; ++k) a += ys[rr][k] * wl[k];
        out[(size_t)(b0 + rr) * 4 + o] = a;
    }
}

// ---------------------------------------------------------------------------
extern "C" void kernel_launch(void* const* d_in, const int* in_sizes, int n_in,
                              void* d_out, int out_size, void* d_ws, size_t ws_size,
                              hipStream_t stream) {
    const int*   s1   = (const int*)d_in[0];
    const int*   s2   = (const int*)d_in[1];
    const int*   l1   = (const int*)d_in[2];
    const int*   l2   = (const int*)d_in[3];
    // d_in[4], d_in[5] (s1_s, s2_s) unused by the reference
    const float* emb  = (const float*)d_in[6];
    const float* Wih1 = (const float*)d_in[7];
    const float* Whh1 = (const float*)d_in[8];
    const float* bih1 = (const float*)d_in[9];
    const float* bhh1 = (const float*)d_in[10];
    const float* Wih2 = (const float*)d_in[11];
    const float* Whh2 = (const float*)d_in[12];
    const float* bih2 = (const float*)d_in[13];
    const float* bhh2 = (const float*)d_in[14];
    const float* Wl1  = (const float*)d_in[15];
    const float* bl1  = (const float*)d_in[16];
    const float* Wl2  = (const float*)d_in[17];
    const float* bl2  = (const float*)d_in[18];
    float* out = (float*)d_out;

    float* tab1 = (float*)d_ws;                       // [V,256] fp32, unit-major
    float* tab2 = tab1 + (size_t)Vv * 256;            // [V,256] fp32  (65.6 MB)

    dim3 grid((Vv + MB - 1) / MB, 2);
    build_tables<<<grid, 256, 0, stream>>>(emb, Wih1, bih1, bhh1,
                                           Wih2, bih2, bhh2, tab1, tab2);
    lstm_main<<<Bsz / 4, 256, 0, stream>>>(s1, s2, l1, l2, tab1, tab2,
                                           Whh1, Whh2, Wl1, bl1, Wl2, bl2, out);
}